// Round 6
// baseline (249.153 us; speedup 1.0000x reference)
//
#include <hip/hip_runtime.h>
#include <math.h>

#define LSEQ 4096
#define DD 768
#define NST 16
#define RNK 48
#define TCH 32
#define NCH (LSEQ / TCH)   // 128 chunks
#define LTILE 8

__device__ __forceinline__ float softplus_f(float z) {
    return fmaxf(z, 0.0f) + log1pf(expf(-fabsf(z)));
}

__device__ __forceinline__ float soft_clamp_f(float v) {
    const float ctr = 5.00005f;
    const float hr  = 4.99995f;
    const float inv_hr = 1.0f / 4.99995f;
    return ctr + hr * tanhf((v - ctr) * inv_hr);
}

__device__ __forceinline__ float wave_sum(float v) {
    #pragma unroll
    for (int m = 32; m >= 1; m >>= 1) v += __shfl_xor(v, m, 64);
    return v;
}

// ---------------------------------------------------------------------------
// Kernel 1: per 8-timestep tile:
//   t = x@W_dt (8x48), bc = x@W_bc (8x32) -> global
//   delta = soft_clamp(rmsnorm(softplus(t@W_dtp + b_dt)) * rms_scale)
// v3: x_t padded to [DD][12] (8-way not 16-way write conflict, b128 reads OK),
//     phase A: thread owns 2 cols x 8 rows -> 16 FMA per 2 LDS reads.
// ---------------------------------------------------------------------------
__global__ __launch_bounds__(512) void k_proj(
    const float* __restrict__ x, const float* __restrict__ W_bc,
    const float* __restrict__ W_dt, const float* __restrict__ W_dtp,
    const float* __restrict__ b_dt, const float* __restrict__ rms_scale,
    float* __restrict__ delta_out, float* __restrict__ bc_out)
{
    __shared__ __align__(16) float x_t[DD][12];      // 36 KB (row 48B, 16B-aligned)
    __shared__ __align__(16) float t_lds[LTILE][RNK];// 1.5 KB
    __shared__ float red[12][LTILE * 80];            // 30 KB
    __shared__ float red2[8][LTILE];

    const int tid = threadIdx.x;
    const int l0  = blockIdx.x * LTILE;

    // transpose-stage x (global coalesced; LDS writes spread over 8 banks)
    for (int i = tid; i < LTILE * DD; i += 512) {
        int li = i / DD, d = i - li * DD;
        x_t[d][li] = x[(size_t)(l0 + li) * DD + d];
    }
    __syncthreads();

    // ---- phase A: t (48 cols) + bc (32 cols) ----
    // thread = (p: K-slice of 64 d, q: column pair). 480 active.
    {
        const int p = tid / 40;
        const int q = tid - p * 40;
        if (p < 12) {
            const int j0 = 2 * q;                    // even, never straddles 48
            float a0[LTILE], a1[LTILE];
            #pragma unroll
            for (int li = 0; li < LTILE; ++li) { a0[li] = 0.f; a1[li] = 0.f; }
            const int dbase = p * 64;
            const int stride = (j0 < RNK) ? RNK : 32;
            const float* Wp = (j0 < RNK) ? (W_dt + (size_t)dbase * RNK + j0)
                                         : (W_bc + (size_t)dbase * 32 + (j0 - RNK));
            for (int i = 0; i < 64; ++i) {
                const int d = dbase + i;
                float4 xa = *(const float4*)&x_t[d][0];
                float4 xb = *(const float4*)&x_t[d][4];
                float2 w = *(const float2*)Wp; Wp += stride;
                a0[0] = fmaf(xa.x, w.x, a0[0]); a1[0] = fmaf(xa.x, w.y, a1[0]);
                a0[1] = fmaf(xa.y, w.x, a0[1]); a1[1] = fmaf(xa.y, w.y, a1[1]);
                a0[2] = fmaf(xa.z, w.x, a0[2]); a1[2] = fmaf(xa.z, w.y, a1[2]);
                a0[3] = fmaf(xa.w, w.x, a0[3]); a1[3] = fmaf(xa.w, w.y, a1[3]);
                a0[4] = fmaf(xb.x, w.x, a0[4]); a1[4] = fmaf(xb.x, w.y, a1[4]);
                a0[5] = fmaf(xb.y, w.x, a0[5]); a1[5] = fmaf(xb.y, w.y, a1[5]);
                a0[6] = fmaf(xb.z, w.x, a0[6]); a1[6] = fmaf(xb.z, w.y, a1[6]);
                a0[7] = fmaf(xb.w, w.x, a0[7]); a1[7] = fmaf(xb.w, w.y, a1[7]);
            }
            #pragma unroll
            for (int li = 0; li < LTILE; ++li)
                *(float2*)&red[p][li * 80 + j0] = make_float2(a0[li], a1[li]);
        }
    }
    __syncthreads();
    for (int idx = tid; idx < LTILE * 80; idx += 512) {
        float s = 0.f;
        #pragma unroll
        for (int p = 0; p < 12; ++p) s += red[p][idx];
        int li = idx / 80, jj = idx - 80 * li;
        if (jj < RNK) t_lds[li][jj] = s;
        else          bc_out[(size_t)(l0 + li) * 32 + (jj - RNK)] = s;
    }
    __syncthreads();

    // ---- phase B: delta = soft_clamp(rmsnorm(softplus(t @ W_dtp + b))) ----
    const int d0 = tid;
    const int d1 = tid + 512;
    const bool has2 = (tid < 256);

    float z0[LTILE], z1[LTILE];
    float bb0 = b_dt[d0];
    float rs0 = rms_scale[d0];
    float bb1 = has2 ? b_dt[d1] : 0.f;
    float rs1 = has2 ? rms_scale[d1] : 0.f;
    #pragma unroll
    for (int li = 0; li < LTILE; ++li) { z0[li] = bb0; z1[li] = bb1; }

    for (int r4 = 0; r4 < RNK; r4 += 4) {
        float4 t4[LTILE];
        #pragma unroll
        for (int li = 0; li < LTILE; ++li)
            t4[li] = *(const float4*)&t_lds[li][r4];
        float w0[4], w1[4];
        #pragma unroll
        for (int k = 0; k < 4; ++k) {
            w0[k] = W_dtp[(r4 + k) * DD + d0];
            w1[k] = has2 ? W_dtp[(r4 + k) * DD + d1] : 0.f;
        }
        #pragma unroll
        for (int li = 0; li < LTILE; ++li) {
            z0[li] = fmaf(t4[li].x, w0[0], z0[li]);
            z0[li] = fmaf(t4[li].y, w0[1], z0[li]);
            z0[li] = fmaf(t4[li].z, w0[2], z0[li]);
            z0[li] = fmaf(t4[li].w, w0[3], z0[li]);
            z1[li] = fmaf(t4[li].x, w1[0], z1[li]);
            z1[li] = fmaf(t4[li].y, w1[1], z1[li]);
            z1[li] = fmaf(t4[li].z, w1[2], z1[li]);
            z1[li] = fmaf(t4[li].w, w1[3], z1[li]);
        }
    }
    float sp0[LTILE], sp1[LTILE];
    #pragma unroll
    for (int li = 0; li < LTILE; ++li) {
        sp0[li] = softplus_f(z0[li]);
        sp1[li] = has2 ? softplus_f(z1[li]) : 0.f;
    }

    const int wid = tid >> 6, lane = tid & 63;
    #pragma unroll
    for (int li = 0; li < LTILE; ++li) {
        float ss = wave_sum(sp0[li] * sp0[li] + sp1[li] * sp1[li]);
        if (lane == 0) red2[wid][li] = ss;
    }
    __syncthreads();
    #pragma unroll
    for (int li = 0; li < LTILE; ++li) {
        float tot = 0.f;
        #pragma unroll
        for (int k = 0; k < 8; ++k) tot += red2[k][li];
        float inv = rsqrtf(tot * (1.0f / DD) + 1e-6f);
        delta_out[(size_t)(l0 + li) * DD + d0] = soft_clamp_f(sp0[li] * inv * rs0);
        if (has2)
            delta_out[(size_t)(l0 + li) * DD + d1] = soft_clamp_f(sp1[li] * inv * rs1);
    }
}

// ---------------------------------------------------------------------------
// Scan pass 1 (4-way state split, quarters intra-wave):
// lane = q*16 + d_lo; block covers 64 d x 4 q. Local scan h=0;
// store prod(a), h_end at [(c*16 + q*4 + n)*768 + d].
// ---------------------------------------------------------------------------
__global__ __launch_bounds__(256) void k_scan1(
    const float* __restrict__ x, const float* __restrict__ delta,
    const float* __restrict__ bc, const float* __restrict__ A_log,
    float* __restrict__ Pbuf, float* __restrict__ Hbuf)
{
    const int lane = threadIdx.x & 63;
    const int w    = threadIdx.x >> 6;
    const int q    = lane >> 4;                 // 0..3
    const int d    = blockIdx.x * 64 + (lane & 15) + w * 16;
    const int c    = blockIdx.y;
    const int l0   = c * TCH;

    float An[4];
    {
        float4 a = *(const float4*)&A_log[d * NST + q * 4];
        An[0] = -expf(a.x); An[1] = -expf(a.y);
        An[2] = -expf(a.z); An[3] = -expf(a.w);
    }
    float h[4] = {0.f, 0.f, 0.f, 0.f};
    float Pp[4] = {1.f, 1.f, 1.f, 1.f};

    float xprev = (l0 == 0) ? 0.f : x[(size_t)(l0 - 1) * DD + d];
    float dv = delta[(size_t)l0 * DD + d];
    float xv = x[(size_t)l0 * DD + d];
    const float4* bcv = (const float4*)bc;
    float4 Bv = bcv[l0 * 8 + q];

    for (int ll = 0; ll < TCH; ++ll) {
        const int l = l0 + ll;
        const int lnx = (l + 1 < LSEQ) ? l + 1 : l;
        float dv_c = dv, xv_c = xv;
        float4 Bc = Bv;
        dv = delta[(size_t)lnx * DD + d];
        xv = x[(size_t)lnx * DD + d];
        Bv = bcv[lnx * 8 + q];

        float xin = 0.5f * (xv_c + xprev);
        xprev = xv_c;
        float c0 = 0.5f * dv_c;
        float c1 = sqrtf(dv_c) * xin;
        float Bs[4] = {Bc.x, Bc.y, Bc.z, Bc.w};
        #pragma unroll
        for (int n = 0; n < 4; ++n) {
            float denom = fmaf(-c0, An[n], 1.0f);    // 1 - 0.5*delta*A
            float inv = __builtin_amdgcn_rcpf(denom);
            float t1 = 2.0f - denom;                 // 1 + 0.5*delta*A
            Pp[n] *= t1 * inv;                       // *= a
            h[n] = fmaf(t1, h[n], c1 * Bs[n]) * inv; // a*h + b
        }
    }
    #pragma unroll
    for (int n = 0; n < 4; ++n) {
        int idx = (c * NST + q * 4 + n) * DD + d;
        Pbuf[idx] = Pp[n];
        Hbuf[idx] = h[n];
    }
}

// ---------------------------------------------------------------------------
// Scan pass 2: wave-parallel chunk-carry. One wave per (d,n) series.
// Lane k owns chunks 2k,2k+1; compose; Hillis-Steele over 64 lanes.
// Overwrites Pbuf with carry-IN h of each chunk.
// ---------------------------------------------------------------------------
__global__ __launch_bounds__(256) void k_scan2(
    float* __restrict__ Pbuf, const float* __restrict__ Hbuf)
{
    const int lane = threadIdx.x & 63;
    const int s = blockIdx.x * 4 + (threadIdx.x >> 6);  // series 0..12287
    const int d = s % DD;
    const int n = s / DD;

    const int c0 = 2 * lane;
    const int idx0 = (c0 * NST + n) * DD + d;
    const int idx1 = ((c0 + 1) * NST + n) * DD + d;
    float p0 = Pbuf[idx0], h0 = Hbuf[idx0];
    float p1 = Pbuf[idx1], h1 = Hbuf[idx1];

    float P = p1 * p0;
    float H = fmaf(p1, h0, h1);

    #pragma unroll
    for (int ofs = 1; ofs < 64; ofs <<= 1) {
        float Pp = __shfl_up(P, ofs, 64);
        float Hp = __shfl_up(H, ofs, 64);
        if (lane >= ofs) {
            H = fmaf(P, Hp, H);
            P = P * Pp;
        }
    }
    float Hex = __shfl_up(H, 1, 64);
    if (lane == 0) Hex = 0.f;

    float carry0 = Hex;
    float carry1 = fmaf(p0, carry0, h0);
    Pbuf[idx0] = carry0;
    Pbuf[idx1] = carry1;
}

// ---------------------------------------------------------------------------
// Scan pass 3 (4-way split, shfl y-reduction, no barriers/LDS):
// redo local scan seeded with carry-in; y = sum_n C*h + D*x.
// ---------------------------------------------------------------------------
__global__ __launch_bounds__(256) void k_scan3(
    const float* __restrict__ x, const float* __restrict__ delta,
    const float* __restrict__ bc, const float* __restrict__ A_log,
    const float* __restrict__ carryin, const float* __restrict__ D_param,
    float* __restrict__ out)
{
    const int lane = threadIdx.x & 63;
    const int w    = threadIdx.x >> 6;
    const int q    = lane >> 4;                 // 0..3
    const int d    = blockIdx.x * 64 + (lane & 15) + w * 16;
    const int c    = blockIdx.y;
    const int l0   = c * TCH;

    float An[4];
    {
        float4 a = *(const float4*)&A_log[d * NST + q * 4];
        An[0] = -expf(a.x); An[1] = -expf(a.y);
        An[2] = -expf(a.z); An[3] = -expf(a.w);
    }
    float h[4];
    #pragma unroll
    for (int n = 0; n < 4; ++n)
        h[n] = carryin[(c * NST + q * 4 + n) * DD + d];
    const float Dp = D_param[d];

    float xprev = (l0 == 0) ? 0.f : x[(size_t)(l0 - 1) * DD + d];
    float dv = delta[(size_t)l0 * DD + d];
    float xv = x[(size_t)l0 * DD + d];
    const float4* bcv = (const float4*)bc;
    float4 Bv = bcv[l0 * 8 + q];
    float4 Cv = bcv[l0 * 8 + 4 + q];

    for (int ll = 0; ll < TCH; ++ll) {
        const int l = l0 + ll;
        const int lnx = (l + 1 < LSEQ) ? l + 1 : l;
        float dv_c = dv, xv_c = xv;
        float4 Bc = Bv, Cc = Cv;
        dv = delta[(size_t)lnx * DD + d];
        xv = x[(size_t)lnx * DD + d];
        Bv = bcv[lnx * 8 + q];
        Cv = bcv[lnx * 8 + 4 + q];

        float xin = 0.5f * (xv_c + xprev);
        xprev = xv_c;
        float c0 = 0.5f * dv_c;
        float c1 = sqrtf(dv_c) * xin;
        float Bs[4] = {Bc.x, Bc.y, Bc.z, Bc.w};
        float Cs[4] = {Cc.x, Cc.y, Cc.z, Cc.w};
        float y = 0.f;
        #pragma unroll
        for (int n = 0; n < 4; ++n) {
            float denom = fmaf(-c0, An[n], 1.0f);
            float inv = __builtin_amdgcn_rcpf(denom);
            float t1 = 2.0f - denom;
            h[n] = fmaf(t1, h[n], c1 * Bs[n]) * inv;
            y = fmaf(Cs[n], h[n], y);
        }
        y += __shfl_xor(y, 16, 64);
        y += __shfl_xor(y, 32, 64);
        if (q == 0)
            out[(size_t)l * DD + d] = fmaf(Dp, xv_c, y);
    }
}

extern "C" void kernel_launch(void* const* d_in, const int* in_sizes, int n_in,
                              void* d_out, int out_size, void* d_ws, size_t ws_size,
                              hipStream_t stream) {
    const float* x         = (const float*)d_in[0];
    const float* A_log     = (const float*)d_in[1];
    const float* D_param   = (const float*)d_in[2];
    const float* W_bc      = (const float*)d_in[3];
    const float* W_dt      = (const float*)d_in[4];
    const float* W_dtp     = (const float*)d_in[5];
    const float* b_dt      = (const float*)d_in[6];
    const float* rms_scale = (const float*)d_in[7];
    float* out = (float*)d_out;

    float* ws    = (float*)d_ws;
    float* delta = ws;                               // L*D
    float* bcbuf = delta + (size_t)LSEQ * DD;        // L*32
    float* Pbuf  = bcbuf + (size_t)LSEQ * 32;        // NCH*16*D
    float* Hbuf  = Pbuf + (size_t)NCH * NST * DD;    // NCH*16*D

    k_proj<<<LSEQ / LTILE, 512, 0, stream>>>(x, W_bc, W_dt, W_dtp, b_dt,
                                             rms_scale, delta, bcbuf);
    k_scan1<<<dim3(DD / 64, NCH), 256, 0, stream>>>(x, delta, bcbuf, A_log,
                                                    Pbuf, Hbuf);
    k_scan2<<<(DD * NST) / 4, 256, 0, stream>>>(Pbuf, Hbuf);
    k_scan3<<<dim3(DD / 64, NCH), 256, 0, stream>>>(x, delta, bcbuf, A_log,
                                                    Pbuf, D_param, out);
}

// Round 7
// 120.191 us; speedup vs baseline: 2.0730x; 2.0730x over previous
//
#include <hip/hip_runtime.h>
#include <math.h>

#define LSEQ 4096
#define DD 768
#define NST 16
#define RNK 48
#define TCH 32
#define NCH (LSEQ / TCH)   // 128 chunks
#define LTILE 8
#define XPAD 772           // 768 + 4: row stride, 16B-aligned, banks spread per li

__device__ __forceinline__ float softplus_f(float z) {
    return fmaxf(z, 0.0f) + log1pf(expf(-fabsf(z)));
}

__device__ __forceinline__ float soft_clamp_f(float v) {
    const float ctr = 5.00005f;
    const float hr  = 4.99995f;
    const float inv_hr = 1.0f / 4.99995f;
    return ctr + hr * tanhf((v - ctr) * inv_hr);
}

__device__ __forceinline__ float wave_sum(float v) {
    #pragma unroll
    for (int m = 32; m >= 1; m >>= 1) v += __shfl_xor(v, m, 64);
    return v;
}

// ---------------------------------------------------------------------------
// Kernel 1 (v4): per 8-row tile.
//   Phase A: [8x768]@[768x80] via 20 col-groups (4 cols, float4 acc)
//            x 12 K-slices (64 d) = 240 threads; x row-major in LDS
//            (b128 reads along d, 16 FMA per b128); W float4 from global.
//   Phase B: z = t@W_dtp + b, 256 thr x 3 d, t as float4 broadcasts.
//   Registers bounded: acc 32, phase B ~80. No big unrolls.
// ---------------------------------------------------------------------------
__global__ __launch_bounds__(256) void k_proj(
    const float* __restrict__ x, const float* __restrict__ W_bc,
    const float* __restrict__ W_dt, const float* __restrict__ W_dtp,
    const float* __restrict__ b_dt, const float* __restrict__ rms_scale,
    float* __restrict__ delta_out, float* __restrict__ bc_out)
{
    __shared__ __align__(16) float x_s[LTILE][XPAD];     // 24.7 KB
    __shared__ __align__(16) float red[12][LTILE * 80];  // 30 KB
    __shared__ __align__(16) float t_lds[LTILE][RNK];    // 1.5 KB
    __shared__ float red2[4][LTILE];

    const int tid = threadIdx.x;
    const int l0  = blockIdx.x * LTILE;

    // stage x rows (coalesced global reads, linear conflict-free LDS writes)
    for (int i = tid; i < LTILE * DD; i += 256) {
        int li = i / DD, d = i - li * DD;
        x_s[li][d] = x[(size_t)(l0 + li) * DD + d];
    }
    __syncthreads();

    // ---- phase A ----
    if (tid < 240) {
        const int q = tid % 20;          // col group, j0 = 4q
        const int p = tid / 20;          // K-slice 0..11, d in [64p, 64p+64)
        const int j0 = 4 * q;
        const int dbase = p * 64;
        const int wstride = (j0 < RNK) ? RNK : 32;
        const float* Wb = (j0 < RNK) ? (W_dt + (size_t)dbase * RNK + j0)
                                     : (W_bc + (size_t)dbase * 32 + (j0 - RNK));
        float4 acc[LTILE];
        #pragma unroll
        for (int li = 0; li < LTILE; ++li)
            acc[li] = make_float4(0.f, 0.f, 0.f, 0.f);

        for (int c = 0; c < 16; ++c) {
            const int cc = (c + p) & 15;         // rotate per p: de-bank-conflict
            const int i4 = cc * 4;               // local d offset
            const float* Wp = Wb + (size_t)i4 * wstride;
            float4 wd0 = *(const float4*)(Wp);
            float4 wd1 = *(const float4*)(Wp + wstride);
            float4 wd2 = *(const float4*)(Wp + 2 * wstride);
            float4 wd3 = *(const float4*)(Wp + 3 * wstride);
            #pragma unroll
            for (int li = 0; li < LTILE; ++li) {
                float4 xv = *(const float4*)&x_s[li][dbase + i4];
                acc[li].x = fmaf(xv.x, wd0.x, acc[li].x);
                acc[li].y = fmaf(xv.x, wd0.y, acc[li].y);
                acc[li].z = fmaf(xv.x, wd0.z, acc[li].z);
                acc[li].w = fmaf(xv.x, wd0.w, acc[li].w);
                acc[li].x = fmaf(xv.y, wd1.x, acc[li].x);
                acc[li].y = fmaf(xv.y, wd1.y, acc[li].y);
                acc[li].z = fmaf(xv.y, wd1.z, acc[li].z);
                acc[li].w = fmaf(xv.y, wd1.w, acc[li].w);
                acc[li].x = fmaf(xv.z, wd2.x, acc[li].x);
                acc[li].y = fmaf(xv.z, wd2.y, acc[li].y);
                acc[li].z = fmaf(xv.z, wd2.z, acc[li].z);
                acc[li].w = fmaf(xv.z, wd2.w, acc[li].w);
                acc[li].x = fmaf(xv.w, wd3.x, acc[li].x);
                acc[li].y = fmaf(xv.w, wd3.y, acc[li].y);
                acc[li].z = fmaf(xv.w, wd3.z, acc[li].z);
                acc[li].w = fmaf(xv.w, wd3.w, acc[li].w);
            }
        }
        #pragma unroll
        for (int li = 0; li < LTILE; ++li)
            *(float4*)&red[p][li * 80 + j0] = acc[li];
    }
    __syncthreads();

    // reduce 12 partials -> t_lds / bc_out
    for (int idx = tid; idx < LTILE * 80; idx += 256) {
        float s = 0.f;
        #pragma unroll
        for (int p = 0; p < 12; ++p) s += red[p][idx];
        int li = idx / 80, jj = idx - 80 * li;
        if (jj < RNK) t_lds[li][jj] = s;
        else          bc_out[(size_t)(l0 + li) * 32 + (jj - RNK)] = s;
    }
    __syncthreads();

    // ---- phase B: 3 d's per thread ----
    const int dA = tid, dB = tid + 256, dC = tid + 512;
    float zA[LTILE], zB[LTILE], zC[LTILE];
    {
        float bA = b_dt[dA], bB = b_dt[dB], bC = b_dt[dC];
        #pragma unroll
        for (int li = 0; li < LTILE; ++li) { zA[li] = bA; zB[li] = bB; zC[li] = bC; }
    }
    #pragma unroll 2
    for (int r4 = 0; r4 < RNK; r4 += 4) {
        float wA0 = W_dtp[(r4 + 0) * DD + dA];
        float wA1 = W_dtp[(r4 + 1) * DD + dA];
        float wA2 = W_dtp[(r4 + 2) * DD + dA];
        float wA3 = W_dtp[(r4 + 3) * DD + dA];
        float wB0 = W_dtp[(r4 + 0) * DD + dB];
        float wB1 = W_dtp[(r4 + 1) * DD + dB];
        float wB2 = W_dtp[(r4 + 2) * DD + dB];
        float wB3 = W_dtp[(r4 + 3) * DD + dB];
        float wC0 = W_dtp[(r4 + 0) * DD + dC];
        float wC1 = W_dtp[(r4 + 1) * DD + dC];
        float wC2 = W_dtp[(r4 + 2) * DD + dC];
        float wC3 = W_dtp[(r4 + 3) * DD + dC];
        #pragma unroll
        for (int li = 0; li < LTILE; ++li) {
            float4 t4 = *(const float4*)&t_lds[li][r4];
            zA[li] = fmaf(t4.x, wA0, zA[li]);
            zA[li] = fmaf(t4.y, wA1, zA[li]);
            zA[li] = fmaf(t4.z, wA2, zA[li]);
            zA[li] = fmaf(t4.w, wA3, zA[li]);
            zB[li] = fmaf(t4.x, wB0, zB[li]);
            zB[li] = fmaf(t4.y, wB1, zB[li]);
            zB[li] = fmaf(t4.z, wB2, zB[li]);
            zB[li] = fmaf(t4.w, wB3, zB[li]);
            zC[li] = fmaf(t4.x, wC0, zC[li]);
            zC[li] = fmaf(t4.y, wC1, zC[li]);
            zC[li] = fmaf(t4.z, wC2, zC[li]);
            zC[li] = fmaf(t4.w, wC3, zC[li]);
        }
    }
    // softplus (in place: z -> sp)
    #pragma unroll
    for (int li = 0; li < LTILE; ++li) {
        zA[li] = softplus_f(zA[li]);
        zB[li] = softplus_f(zB[li]);
        zC[li] = softplus_f(zC[li]);
    }
    // RMS partials per wave
    const int wid = tid >> 6;
    const int lane = tid & 63;
    #pragma unroll
    for (int li = 0; li < LTILE; ++li) {
        float ss = wave_sum(zA[li] * zA[li] + zB[li] * zB[li] + zC[li] * zC[li]);
        if (lane == 0) red2[wid][li] = ss;
    }
    __syncthreads();
    {
        float rsA = rms_scale[dA], rsB = rms_scale[dB], rsC = rms_scale[dC];
        #pragma unroll
        for (int li = 0; li < LTILE; ++li) {
            float tot = red2[0][li] + red2[1][li] + red2[2][li] + red2[3][li];
            float inv = rsqrtf(tot * (1.0f / DD) + 1e-6f);
            delta_out[(size_t)(l0 + li) * DD + dA] = soft_clamp_f(zA[li] * inv * rsA);
            delta_out[(size_t)(l0 + li) * DD + dB] = soft_clamp_f(zB[li] * inv * rsB);
            delta_out[(size_t)(l0 + li) * DD + dC] = soft_clamp_f(zC[li] * inv * rsC);
        }
    }
}

// ---------------------------------------------------------------------------
// Scan pass 1 (4-way state split, quarters intra-wave):
// lane = q*16 + d_lo; block covers 64 d x 4 q. Local scan h=0;
// store prod(a), h_end at [(c*16 + q*4 + n)*768 + d].
// ---------------------------------------------------------------------------
__global__ __launch_bounds__(256) void k_scan1(
    const float* __restrict__ x, const float* __restrict__ delta,
    const float* __restrict__ bc, const float* __restrict__ A_log,
    float* __restrict__ Pbuf, float* __restrict__ Hbuf)
{
    const int lane = threadIdx.x & 63;
    const int w    = threadIdx.x >> 6;
    const int q    = lane >> 4;                 // 0..3
    const int d    = blockIdx.x * 64 + (lane & 15) + w * 16;
    const int c    = blockIdx.y;
    const int l0   = c * TCH;

    float An[4];
    {
        float4 a = *(const float4*)&A_log[d * NST + q * 4];
        An[0] = -expf(a.x); An[1] = -expf(a.y);
        An[2] = -expf(a.z); An[3] = -expf(a.w);
    }
    float h[4] = {0.f, 0.f, 0.f, 0.f};
    float Pp[4] = {1.f, 1.f, 1.f, 1.f};

    float xprev = (l0 == 0) ? 0.f : x[(size_t)(l0 - 1) * DD + d];
    float dv = delta[(size_t)l0 * DD + d];
    float xv = x[(size_t)l0 * DD + d];
    const float4* bcv = (const float4*)bc;
    float4 Bv = bcv[l0 * 8 + q];

    for (int ll = 0; ll < TCH; ++ll) {
        const int l = l0 + ll;
        const int lnx = (l + 1 < LSEQ) ? l + 1 : l;
        float dv_c = dv, xv_c = xv;
        float4 Bc = Bv;
        dv = delta[(size_t)lnx * DD + d];
        xv = x[(size_t)lnx * DD + d];
        Bv = bcv[lnx * 8 + q];

        float xin = 0.5f * (xv_c + xprev);
        xprev = xv_c;
        float c0 = 0.5f * dv_c;
        float c1 = sqrtf(dv_c) * xin;
        float Bs[4] = {Bc.x, Bc.y, Bc.z, Bc.w};
        #pragma unroll
        for (int n = 0; n < 4; ++n) {
            float denom = fmaf(-c0, An[n], 1.0f);    // 1 - 0.5*delta*A
            float inv = __builtin_amdgcn_rcpf(denom);
            float t1 = 2.0f - denom;                 // 1 + 0.5*delta*A
            Pp[n] *= t1 * inv;                       // *= a
            h[n] = fmaf(t1, h[n], c1 * Bs[n]) * inv; // a*h + b
        }
    }
    #pragma unroll
    for (int n = 0; n < 4; ++n) {
        int idx = (c * NST + q * 4 + n) * DD + d;
        Pbuf[idx] = Pp[n];
        Hbuf[idx] = h[n];
    }
}

// ---------------------------------------------------------------------------
// Scan pass 2: wave-parallel chunk-carry. One wave per (d,n) series.
// Lane k owns chunks 2k,2k+1; compose; Hillis-Steele over 64 lanes.
// Overwrites Pbuf with carry-IN h of each chunk.
// ---------------------------------------------------------------------------
__global__ __launch_bounds__(256) void k_scan2(
    float* __restrict__ Pbuf, const float* __restrict__ Hbuf)
{
    const int lane = threadIdx.x & 63;
    const int s = blockIdx.x * 4 + (threadIdx.x >> 6);  // series 0..12287
    const int d = s % DD;
    const int n = s / DD;

    const int c0 = 2 * lane;
    const int idx0 = (c0 * NST + n) * DD + d;
    const int idx1 = ((c0 + 1) * NST + n) * DD + d;
    float p0 = Pbuf[idx0], h0 = Hbuf[idx0];
    float p1 = Pbuf[idx1], h1 = Hbuf[idx1];

    float P = p1 * p0;
    float H = fmaf(p1, h0, h1);

    #pragma unroll
    for (int ofs = 1; ofs < 64; ofs <<= 1) {
        float Pp = __shfl_up(P, ofs, 64);
        float Hp = __shfl_up(H, ofs, 64);
        if (lane >= ofs) {
            H = fmaf(P, Hp, H);
            P = P * Pp;
        }
    }
    float Hex = __shfl_up(H, 1, 64);
    if (lane == 0) Hex = 0.f;

    float carry0 = Hex;
    float carry1 = fmaf(p0, carry0, h0);
    Pbuf[idx0] = carry0;
    Pbuf[idx1] = carry1;
}

// ---------------------------------------------------------------------------
// Scan pass 3 (4-way split, shfl y-reduction, no barriers/LDS):
// redo local scan seeded with carry-in; y = sum_n C*h + D*x.
// ---------------------------------------------------------------------------
__global__ __launch_bounds__(256) void k_scan3(
    const float* __restrict__ x, const float* __restrict__ delta,
    const float* __restrict__ bc, const float* __restrict__ A_log,
    const float* __restrict__ carryin, const float* __restrict__ D_param,
    float* __restrict__ out)
{
    const int lane = threadIdx.x & 63;
    const int w    = threadIdx.x >> 6;
    const int q    = lane >> 4;                 // 0..3
    const int d    = blockIdx.x * 64 + (lane & 15) + w * 16;
    const int c    = blockIdx.y;
    const int l0   = c * TCH;

    float An[4];
    {
        float4 a = *(const float4*)&A_log[d * NST + q * 4];
        An[0] = -expf(a.x); An[1] = -expf(a.y);
        An[2] = -expf(a.z); An[3] = -expf(a.w);
    }
    float h[4];
    #pragma unroll
    for (int n = 0; n < 4; ++n)
        h[n] = carryin[(c * NST + q * 4 + n) * DD + d];
    const float Dp = D_param[d];

    float xprev = (l0 == 0) ? 0.f : x[(size_t)(l0 - 1) * DD + d];
    float dv = delta[(size_t)l0 * DD + d];
    float xv = x[(size_t)l0 * DD + d];
    const float4* bcv = (const float4*)bc;
    float4 Bv = bcv[l0 * 8 + q];
    float4 Cv = bcv[l0 * 8 + 4 + q];

    for (int ll = 0; ll < TCH; ++ll) {
        const int l = l0 + ll;
        const int lnx = (l + 1 < LSEQ) ? l + 1 : l;
        float dv_c = dv, xv_c = xv;
        float4 Bc = Bv, Cc = Cv;
        dv = delta[(size_t)lnx * DD + d];
        xv = x[(size_t)lnx * DD + d];
        Bv = bcv[lnx * 8 + q];
        Cv = bcv[lnx * 8 + 4 + q];

        float xin = 0.5f * (xv_c + xprev);
        xprev = xv_c;
        float c0 = 0.5f * dv_c;
        float c1 = sqrtf(dv_c) * xin;
        float Bs[4] = {Bc.x, Bc.y, Bc.z, Bc.w};
        float Cs[4] = {Cc.x, Cc.y, Cc.z, Cc.w};
        float y = 0.f;
        #pragma unroll
        for (int n = 0; n < 4; ++n) {
            float denom = fmaf(-c0, An[n], 1.0f);
            float inv = __builtin_amdgcn_rcpf(denom);
            float t1 = 2.0f - denom;
            h[n] = fmaf(t1, h[n], c1 * Bs[n]) * inv;
            y = fmaf(Cs[n], h[n], y);
        }
        y += __shfl_xor(y, 16, 64);
        y += __shfl_xor(y, 32, 64);
        if (q == 0)
            out[(size_t)l * DD + d] = fmaf(Dp, xv_c, y);
    }
}

extern "C" void kernel_launch(void* const* d_in, const int* in_sizes, int n_in,
                              void* d_out, int out_size, void* d_ws, size_t ws_size,
                              hipStream_t stream) {
    const float* x         = (const float*)d_in[0];
    const float* A_log     = (const float*)d_in[1];
    const float* D_param   = (const float*)d_in[2];
    const float* W_bc      = (const float*)d_in[3];
    const float* W_dt      = (const float*)d_in[4];
    const float* W_dtp     = (const float*)d_in[5];
    const float* b_dt      = (const float*)d_in[6];
    const float* rms_scale = (const float*)d_in[7];
    float* out = (float*)d_out;

    float* ws    = (float*)d_ws;
    float* delta = ws;                               // L*D
    float* bcbuf = delta + (size_t)LSEQ * DD;        // L*32
    float* Pbuf  = bcbuf + (size_t)LSEQ * 32;        // NCH*16*D
    float* Hbuf  = Pbuf + (size_t)NCH * NST * DD;    // NCH*16*D

    k_proj<<<LSEQ / LTILE, 256, 0, stream>>>(x, W_bc, W_dt, W_dtp, b_dt,
                                             rms_scale, delta, bcbuf);
    k_scan1<<<dim3(DD / 64, NCH), 256, 0, stream>>>(x, delta, bcbuf, A_log,
                                                    Pbuf, Hbuf);
    k_scan2<<<(DD * NST) / 4, 256, 0, stream>>>(Pbuf, Hbuf);
    k_scan3<<<dim3(DD / 64, NCH), 256, 0, stream>>>(x, delta, bcbuf, A_log,
                                                    Pbuf, D_param, out);
}

// Round 8
// 116.537 us; speedup vs baseline: 2.1380x; 1.0314x over previous
//
#include <hip/hip_runtime.h>
#include <math.h>

#define LSEQ 4096
#define DD 768
#define NST 16
#define RNK 48
#define TCH 32
#define NCH (LSEQ / TCH)   // 128 chunks
#define LTILE 8
#define XPAD 772

__device__ __forceinline__ float softplus_f(float z) {
    return fmaxf(z, 0.0f) + log1pf(expf(-fabsf(z)));
}

__device__ __forceinline__ float soft_clamp_f(float v) {
    const float ctr = 5.00005f;
    const float hr  = 4.99995f;
    const float inv_hr = 1.0f / 4.99995f;
    return ctr + hr * tanhf((v - ctr) * inv_hr);
}

__device__ __forceinline__ float wave_sum(float v) {
    #pragma unroll
    for (int m = 32; m >= 1; m >>= 1) v += __shfl_xor(v, m, 64);
    return v;
}

// ---------------------------------------------------------------------------
// Kernel 1 (v4, unchanged from round 7): projections + delta pipeline.
// ---------------------------------------------------------------------------
__global__ __launch_bounds__(256) void k_proj(
    const float* __restrict__ x, const float* __restrict__ W_bc,
    const float* __restrict__ W_dt, const float* __restrict__ W_dtp,
    const float* __restrict__ b_dt, const float* __restrict__ rms_scale,
    float* __restrict__ delta_out, float* __restrict__ bc_out)
{
    __shared__ __align__(16) float x_s[LTILE][XPAD];
    __shared__ __align__(16) float red[12][LTILE * 80];
    __shared__ __align__(16) float t_lds[LTILE][RNK];
    __shared__ float red2[4][LTILE];

    const int tid = threadIdx.x;
    const int l0  = blockIdx.x * LTILE;

    for (int i = tid; i < LTILE * DD; i += 256) {
        int li = i / DD, d = i - li * DD;
        x_s[li][d] = x[(size_t)(l0 + li) * DD + d];
    }
    __syncthreads();

    if (tid < 240) {
        const int q = tid % 20;
        const int p = tid / 20;
        const int j0 = 4 * q;
        const int dbase = p * 64;
        const int wstride = (j0 < RNK) ? RNK : 32;
        const float* Wb = (j0 < RNK) ? (W_dt + (size_t)dbase * RNK + j0)
                                     : (W_bc + (size_t)dbase * 32 + (j0 - RNK));
        float4 acc[LTILE];
        #pragma unroll
        for (int li = 0; li < LTILE; ++li)
            acc[li] = make_float4(0.f, 0.f, 0.f, 0.f);

        for (int c = 0; c < 16; ++c) {
            const int cc = (c + p) & 15;
            const int i4 = cc * 4;
            const float* Wp = Wb + (size_t)i4 * wstride;
            float4 wd0 = *(const float4*)(Wp);
            float4 wd1 = *(const float4*)(Wp + wstride);
            float4 wd2 = *(const float4*)(Wp + 2 * wstride);
            float4 wd3 = *(const float4*)(Wp + 3 * wstride);
            #pragma unroll
            for (int li = 0; li < LTILE; ++li) {
                float4 xv = *(const float4*)&x_s[li][dbase + i4];
                acc[li].x = fmaf(xv.x, wd0.x, acc[li].x);
                acc[li].y = fmaf(xv.x, wd0.y, acc[li].y);
                acc[li].z = fmaf(xv.x, wd0.z, acc[li].z);
                acc[li].w = fmaf(xv.x, wd0.w, acc[li].w);
                acc[li].x = fmaf(xv.y, wd1.x, acc[li].x);
                acc[li].y = fmaf(xv.y, wd1.y, acc[li].y);
                acc[li].z = fmaf(xv.y, wd1.z, acc[li].z);
                acc[li].w = fmaf(xv.y, wd1.w, acc[li].w);
                acc[li].x = fmaf(xv.z, wd2.x, acc[li].x);
                acc[li].y = fmaf(xv.z, wd2.y, acc[li].y);
                acc[li].z = fmaf(xv.z, wd2.z, acc[li].z);
                acc[li].w = fmaf(xv.z, wd2.w, acc[li].w);
                acc[li].x = fmaf(xv.w, wd3.x, acc[li].x);
                acc[li].y = fmaf(xv.w, wd3.y, acc[li].y);
                acc[li].z = fmaf(xv.w, wd3.z, acc[li].z);
                acc[li].w = fmaf(xv.w, wd3.w, acc[li].w);
            }
        }
        #pragma unroll
        for (int li = 0; li < LTILE; ++li)
            *(float4*)&red[p][li * 80 + j0] = acc[li];
    }
    __syncthreads();

    for (int idx = tid; idx < LTILE * 80; idx += 256) {
        float s = 0.f;
        #pragma unroll
        for (int p = 0; p < 12; ++p) s += red[p][idx];
        int li = idx / 80, jj = idx - 80 * li;
        if (jj < RNK) t_lds[li][jj] = s;
        else          bc_out[(size_t)(l0 + li) * 32 + (jj - RNK)] = s;
    }
    __syncthreads();

    const int dA = tid, dB = tid + 256, dC = tid + 512;
    float zA[LTILE], zB[LTILE], zC[LTILE];
    {
        float bA = b_dt[dA], bB = b_dt[dB], bC = b_dt[dC];
        #pragma unroll
        for (int li = 0; li < LTILE; ++li) { zA[li] = bA; zB[li] = bB; zC[li] = bC; }
    }
    #pragma unroll 2
    for (int r4 = 0; r4 < RNK; r4 += 4) {
        float wA0 = W_dtp[(r4 + 0) * DD + dA];
        float wA1 = W_dtp[(r4 + 1) * DD + dA];
        float wA2 = W_dtp[(r4 + 2) * DD + dA];
        float wA3 = W_dtp[(r4 + 3) * DD + dA];
        float wB0 = W_dtp[(r4 + 0) * DD + dB];
        float wB1 = W_dtp[(r4 + 1) * DD + dB];
        float wB2 = W_dtp[(r4 + 2) * DD + dB];
        float wB3 = W_dtp[(r4 + 3) * DD + dB];
        float wC0 = W_dtp[(r4 + 0) * DD + dC];
        float wC1 = W_dtp[(r4 + 1) * DD + dC];
        float wC2 = W_dtp[(r4 + 2) * DD + dC];
        float wC3 = W_dtp[(r4 + 3) * DD + dC];
        #pragma unroll
        for (int li = 0; li < LTILE; ++li) {
            float4 t4 = *(const float4*)&t_lds[li][r4];
            zA[li] = fmaf(t4.x, wA0, zA[li]);
            zA[li] = fmaf(t4.y, wA1, zA[li]);
            zA[li] = fmaf(t4.z, wA2, zA[li]);
            zA[li] = fmaf(t4.w, wA3, zA[li]);
            zB[li] = fmaf(t4.x, wB0, zB[li]);
            zB[li] = fmaf(t4.y, wB1, zB[li]);
            zB[li] = fmaf(t4.z, wB2, zB[li]);
            zB[li] = fmaf(t4.w, wB3, zB[li]);
            zC[li] = fmaf(t4.x, wC0, zC[li]);
            zC[li] = fmaf(t4.y, wC1, zC[li]);
            zC[li] = fmaf(t4.z, wC2, zC[li]);
            zC[li] = fmaf(t4.w, wC3, zC[li]);
        }
    }
    #pragma unroll
    for (int li = 0; li < LTILE; ++li) {
        zA[li] = softplus_f(zA[li]);
        zB[li] = softplus_f(zB[li]);
        zC[li] = softplus_f(zC[li]);
    }
    const int wid = tid >> 6;
    const int lane = tid & 63;
    #pragma unroll
    for (int li = 0; li < LTILE; ++li) {
        float ss = wave_sum(zA[li] * zA[li] + zB[li] * zB[li] + zC[li] * zC[li]);
        if (lane == 0) red2[wid][li] = ss;
    }
    __syncthreads();
    {
        float rsA = rms_scale[dA], rsB = rms_scale[dB], rsC = rms_scale[dC];
        #pragma unroll
        for (int li = 0; li < LTILE; ++li) {
            float tot = red2[0][li] + red2[1][li] + red2[2][li] + red2[3][li];
            float inv = rsqrtf(tot * (1.0f / DD) + 1e-6f);
            delta_out[(size_t)(l0 + li) * DD + dA] = soft_clamp_f(zA[li] * inv * rsA);
            delta_out[(size_t)(l0 + li) * DD + dB] = soft_clamp_f(zB[li] * inv * rsB);
            delta_out[(size_t)(l0 + li) * DD + dC] = soft_clamp_f(zC[li] * inv * rsC);
        }
    }
}

// ---------------------------------------------------------------------------
// Scan pass 1 (v5: LDS chunk staging). Block = 64 d x chunk; 4-way state
// split intra-wave (lane = q*16 + dlo%16, wave covers 16 d x 4 q).
// Stage x[l0-1..l0+31], delta[l0..l0+31], B cols into LDS; then 32 steps
// with zero global loads. Store prod(a), h_end.
// ---------------------------------------------------------------------------
__global__ __launch_bounds__(256) void k_scan1(
    const float* __restrict__ x, const float* __restrict__ delta,
    const float* __restrict__ bc, const float* __restrict__ A_log,
    float* __restrict__ Pbuf, float* __restrict__ Hbuf)
{
    __shared__ __align__(16) float xs[33 * 64];   // 8.25 KB
    __shared__ __align__(16) float dsv[32 * 64];  // 8 KB
    __shared__ __align__(16) float bs[32 * 16];   // 2 KB (B cols only)

    const int tid = threadIdx.x;
    const int db  = blockIdx.x * 64;
    const int c   = blockIdx.y;
    const int l0  = c * TCH;

    // stage x rows l0-1 .. l0+31
    for (int i = tid; i < 33 * 16; i += 256) {
        int r = i >> 4, f = i & 15;
        int l = l0 - 1 + r;
        float4 v = (l >= 0) ? *(const float4*)&x[(size_t)l * DD + db + f * 4]
                            : make_float4(0.f, 0.f, 0.f, 0.f);
        *(float4*)&xs[r * 64 + f * 4] = v;
    }
    // stage delta rows l0 .. l0+31
    for (int i = tid; i < 32 * 16; i += 256) {
        int r = i >> 4, f = i & 15;
        *(float4*)&dsv[r * 64 + f * 4] =
            *(const float4*)&delta[(size_t)(l0 + r) * DD + db + f * 4];
    }
    // stage B columns (bc[l][0..15])
    for (int i = tid; i < 32 * 4; i += 256) {
        int r = i >> 2, f = i & 3;
        *(float4*)&bs[r * 16 + f * 4] =
            *(const float4*)&bc[(size_t)(l0 + r) * 32 + f * 4];
    }

    const int lane = tid & 63;
    const int w    = tid >> 6;
    const int q    = lane >> 4;
    const int dlo  = (lane & 15) + w * 16;
    const int d    = db + dlo;

    float An[4];
    {
        float4 a = *(const float4*)&A_log[d * NST + q * 4];
        An[0] = -expf(a.x); An[1] = -expf(a.y);
        An[2] = -expf(a.z); An[3] = -expf(a.w);
    }
    __syncthreads();

    float h[4]  = {0.f, 0.f, 0.f, 0.f};
    float Pp[4] = {1.f, 1.f, 1.f, 1.f};
    float xprev = xs[dlo];                       // row 0 = x[l0-1] (or 0)

    for (int ll = 0; ll < TCH; ++ll) {
        float xv  = xs[(ll + 1) * 64 + dlo];
        float dvc = dsv[ll * 64 + dlo];
        float4 Bc = *(const float4*)&bs[ll * 16 + q * 4];

        float xin = 0.5f * (xv + xprev);
        xprev = xv;
        float c0 = 0.5f * dvc;
        float c1 = sqrtf(dvc) * xin;
        float Bs[4] = {Bc.x, Bc.y, Bc.z, Bc.w};
        #pragma unroll
        for (int n = 0; n < 4; ++n) {
            float denom = fmaf(-c0, An[n], 1.0f);
            float inv = __builtin_amdgcn_rcpf(denom);
            float t1 = 2.0f - denom;
            Pp[n] *= t1 * inv;
            h[n] = fmaf(t1, h[n], c1 * Bs[n]) * inv;
        }
    }
    #pragma unroll
    for (int n = 0; n < 4; ++n) {
        int idx = (c * NST + q * 4 + n) * DD + d;
        Pbuf[idx] = Pp[n];
        Hbuf[idx] = h[n];
    }
}

// ---------------------------------------------------------------------------
// Scan pass 2 (unchanged): wave-parallel chunk-carry, one wave per series.
// ---------------------------------------------------------------------------
__global__ __launch_bounds__(256) void k_scan2(
    float* __restrict__ Pbuf, const float* __restrict__ Hbuf)
{
    const int lane = threadIdx.x & 63;
    const int s = blockIdx.x * 4 + (threadIdx.x >> 6);
    const int d = s % DD;
    const int n = s / DD;

    const int c0 = 2 * lane;
    const int idx0 = (c0 * NST + n) * DD + d;
    const int idx1 = ((c0 + 1) * NST + n) * DD + d;
    float p0 = Pbuf[idx0], h0 = Hbuf[idx0];
    float p1 = Pbuf[idx1], h1 = Hbuf[idx1];

    float P = p1 * p0;
    float H = fmaf(p1, h0, h1);

    #pragma unroll
    for (int ofs = 1; ofs < 64; ofs <<= 1) {
        float Pp = __shfl_up(P, ofs, 64);
        float Hp = __shfl_up(H, ofs, 64);
        if (lane >= ofs) {
            H = fmaf(P, Hp, H);
            P = P * Pp;
        }
    }
    float Hex = __shfl_up(H, 1, 64);
    if (lane == 0) Hex = 0.f;

    float carry0 = Hex;
    float carry1 = fmaf(p0, carry0, h0);
    Pbuf[idx0] = carry0;
    Pbuf[idx1] = carry1;
}

// ---------------------------------------------------------------------------
// Scan pass 3 (v5: LDS chunk staging + shfl y-reduction, no global loads in
// the step loop). Redo local scan seeded with carry-in; y = sum C*h + D*x.
// ---------------------------------------------------------------------------
__global__ __launch_bounds__(256) void k_scan3(
    const float* __restrict__ x, const float* __restrict__ delta,
    const float* __restrict__ bc, const float* __restrict__ A_log,
    const float* __restrict__ carryin, const float* __restrict__ D_param,
    float* __restrict__ out)
{
    __shared__ __align__(16) float xs[33 * 64];   // 8.25 KB
    __shared__ __align__(16) float dsv[32 * 64];  // 8 KB
    __shared__ __align__(16) float bs[32 * 32];   // 4 KB (B and C)

    const int tid = threadIdx.x;
    const int db  = blockIdx.x * 64;
    const int c   = blockIdx.y;
    const int l0  = c * TCH;

    for (int i = tid; i < 33 * 16; i += 256) {
        int r = i >> 4, f = i & 15;
        int l = l0 - 1 + r;
        float4 v = (l >= 0) ? *(const float4*)&x[(size_t)l * DD + db + f * 4]
                            : make_float4(0.f, 0.f, 0.f, 0.f);
        *(float4*)&xs[r * 64 + f * 4] = v;
    }
    for (int i = tid; i < 32 * 16; i += 256) {
        int r = i >> 4, f = i & 15;
        *(float4*)&dsv[r * 64 + f * 4] =
            *(const float4*)&delta[(size_t)(l0 + r) * DD + db + f * 4];
    }
    for (int i = tid; i < 32 * 8; i += 256) {
        int r = i >> 3, f = i & 7;
        *(float4*)&bs[r * 32 + f * 4] =
            *(const float4*)&bc[(size_t)(l0 + r) * 32 + f * 4];
    }

    const int lane = tid & 63;
    const int w    = tid >> 6;
    const int q    = lane >> 4;
    const int dlo  = (lane & 15) + w * 16;
    const int d    = db + dlo;

    float An[4];
    {
        float4 a = *(const float4*)&A_log[d * NST + q * 4];
        An[0] = -expf(a.x); An[1] = -expf(a.y);
        An[2] = -expf(a.z); An[3] = -expf(a.w);
    }
    float h[4];
    #pragma unroll
    for (int n = 0; n < 4; ++n)
        h[n] = carryin[(c * NST + q * 4 + n) * DD + d];
    const float Dp = D_param[d];

    __syncthreads();

    float xprev = xs[dlo];
    for (int ll = 0; ll < TCH; ++ll) {
        float xv  = xs[(ll + 1) * 64 + dlo];
        float dvc = dsv[ll * 64 + dlo];
        float4 Bc = *(const float4*)&bs[ll * 32 + q * 4];
        float4 Cc = *(const float4*)&bs[ll * 32 + 16 + q * 4];

        float xin = 0.5f * (xv + xprev);
        xprev = xv;
        float c0 = 0.5f * dvc;
        float c1 = sqrtf(dvc) * xin;
        float Bs[4] = {Bc.x, Bc.y, Bc.z, Bc.w};
        float Cs[4] = {Cc.x, Cc.y, Cc.z, Cc.w};
        float y = 0.f;
        #pragma unroll
        for (int n = 0; n < 4; ++n) {
            float denom = fmaf(-c0, An[n], 1.0f);
            float inv = __builtin_amdgcn_rcpf(denom);
            float t1 = 2.0f - denom;
            h[n] = fmaf(t1, h[n], c1 * Bs[n]) * inv;
            y = fmaf(Cs[n], h[n], y);
        }
        y += __shfl_xor(y, 16, 64);
        y += __shfl_xor(y, 32, 64);
        if (q == 0)
            out[(size_t)(l0 + ll) * DD + d] = fmaf(Dp, xv, y);
    }
}

extern "C" void kernel_launch(void* const* d_in, const int* in_sizes, int n_in,
                              void* d_out, int out_size, void* d_ws, size_t ws_size,
                              hipStream_t stream) {
    const float* x         = (const float*)d_in[0];
    const float* A_log     = (const float*)d_in[1];
    const float* D_param   = (const float*)d_in[2];
    const float* W_bc      = (const float*)d_in[3];
    const float* W_dt      = (const float*)d_in[4];
    const float* W_dtp     = (const float*)d_in[5];
    const float* b_dt      = (const float*)d_in[6];
    const float* rms_scale = (const float*)d_in[7];
    float* out = (float*)d_out;

    float* ws    = (float*)d_ws;
    float* delta = ws;                               // L*D
    float* bcbuf = delta + (size_t)LSEQ * DD;        // L*32
    float* Pbuf  = bcbuf + (size_t)LSEQ * 32;        // NCH*16*D
    float* Hbuf  = Pbuf + (size_t)NCH * NST * DD;    // NCH*16*D

    k_proj<<<LSEQ / LTILE, 256, 0, stream>>>(x, W_bc, W_dt, W_dtp, b_dt,
                                             rms_scale, delta, bcbuf);
    k_scan1<<<dim3(DD / 64, NCH), 256, 0, stream>>>(x, delta, bcbuf, A_log,
                                                    Pbuf, Hbuf);
    k_scan2<<<(DD * NST) / 4, 256, 0, stream>>>(Pbuf, Hbuf);
    k_scan3<<<dim3(DD / 64, NCH), 256, 0, stream>>>(x, delta, bcbuf, A_log,
                                                    Pbuf, D_param, out);
}